// Round 1
// baseline (374.762 us; speedup 1.0000x reference)
//
#include <hip/hip_runtime.h>
#include <hip/hip_bf16.h>

#define BB 16
#define NN 12
#define NE 144
#define TT 128
#define CC 128

typedef __attribute__((ext_vector_type(8))) short v8s;   // 8 x bf16
typedef __attribute__((ext_vector_type(4))) float v4f;   // mfma accumulator

__device__ __forceinline__ short f2bf(float f) {
    unsigned u = __float_as_uint(f);
    u += 0x7fffu + ((u >> 16) & 1u);        // RNE
    return (short)(u >> 16);
}

__device__ __forceinline__ v8s frag_from_f32(const float4* p) {
    float4 a = p[0], b = p[1];
    v8s r;
    r[0] = f2bf(a.x); r[1] = f2bf(a.y); r[2] = f2bf(a.z); r[3] = f2bf(a.w);
    r[4] = f2bf(b.x); r[5] = f2bf(b.y); r[6] = f2bf(b.z); r[7] = f2bf(b.w);
    return r;
}

// ---------------- weights -> bf16 ----------------
__global__ __launch_bounds__(256) void kW(
    const float* A1, const float* B1, const float* E1, const float* U1, const float* V1,
    const float* A2, const float* B2, const float* E2, const float* U2, const float* V2,
    unsigned short* wb)
{
    int idx = blockIdx.x * 256 + threadIdx.x;   // 10*16384 = 163840 total
    int w = idx >> 14, r = idx & 16383;
    const float* s;
    switch (w) {
        case 0: s = A1; break; case 1: s = B1; break; case 2: s = E1; break;
        case 3: s = U1; break; case 4: s = V1; break; case 5: s = A2; break;
        case 6: s = B2; break; case 7: s = E2; break; case 8: s = U2; break;
        default: s = V2; break;
    }
    wb[idx] = (unsigned short)f2bf(s[r]);
}

// ---------------- P: x @ {A,B,V,U}^T ----------------
__global__ __launch_bounds__(256) void kP(
    const float* __restrict__ x, const unsigned short* __restrict__ wb,
    int sA, int sB, int sV, int sU,
    float* __restrict__ oA, float* __restrict__ oB,
    float* __restrict__ oV, float* __restrict__ oU)
{
    __shared__ float4 xt4[64][33];
    int tid = threadIdx.x;
    int m0 = blockIdx.x * 64;
    #pragma unroll
    for (int it = 0; it < 8; ++it) {
        int f = it * 256 + tid;
        int row = f >> 5, c4 = f & 31;
        xt4[row][c4] = *reinterpret_cast<const float4*>(x + (size_t)m0 * 128 + (size_t)f * 4);
    }
    __syncthreads();
    int lane = tid & 63, wid = tid >> 6;
    int l15 = lane & 15, l4 = lane >> 4;

    const unsigned short* Ws[4] = { wb + (size_t)sA * 16384, wb + (size_t)sB * 16384,
                                    wb + (size_t)sV * 16384, wb + (size_t)sU * 16384 };
    float* Os[4] = { oA, oB, oV, oU };

    #pragma unroll
    for (int w = 0; w < 4; ++w) {
        const unsigned short* W = Ws[w];
        float* out = Os[w];
        v8s bfr[2][4];
        #pragma unroll
        for (int nt2 = 0; nt2 < 2; ++nt2) {
            int col = (wid * 2 + nt2) * 16 + l15;
            #pragma unroll
            for (int kk = 0; kk < 4; ++kk)
                bfr[nt2][kk] = *reinterpret_cast<const v8s*>(W + col * 128 + kk * 32 + l4 * 8);
        }
        v4f acc[4][2] = {};
        #pragma unroll
        for (int kk = 0; kk < 4; ++kk) {
            #pragma unroll
            for (int mt = 0; mt < 4; ++mt) {
                v8s a = frag_from_f32(&xt4[mt * 16 + l15][kk * 8 + l4 * 2]);
                acc[mt][0] = __builtin_amdgcn_mfma_f32_16x16x32_bf16(a, bfr[0][kk], acc[mt][0], 0, 0, 0);
                acc[mt][1] = __builtin_amdgcn_mfma_f32_16x16x32_bf16(a, bfr[1][kk], acc[mt][1], 0, 0, 0);
            }
        }
        #pragma unroll
        for (int mt = 0; mt < 4; ++mt) {
            #pragma unroll
            for (int nt2 = 0; nt2 < 2; ++nt2) {
                int col = (wid * 2 + nt2) * 16 + l15;
                #pragma unroll
                for (int reg = 0; reg < 4; ++reg) {
                    int rowg = m0 + mt * 16 + l4 * 4 + reg;
                    out[(size_t)rowg * 128 + col] = acc[mt][nt2][reg];
                }
            }
        }
    }
}

// ---------------- A: edge_upd stats ----------------
__global__ __launch_bounds__(256) void kA(
    const float* edge, const float* __restrict__ xA, const float* __restrict__ xB,
    const unsigned short* __restrict__ Ebf, float* __restrict__ epart)
{
    __shared__ float4 et4[48][33];
    __shared__ float4 xab4[16][33];
    __shared__ float srow[48], qrow[48];
    int tid = threadIdx.x;
    int bid = blockIdx.x;
    int third = bid % 3; int bt = bid / 3;
    int b = bt >> 7, t = bt & 127;
    if (tid < 48) { srow[tid] = 0.f; qrow[tid] = 0.f; }
    const float* eb = edge + ((size_t)(b * NE + third * 48) * TT + t) * CC;
    #pragma unroll
    for (int it = 0; it < 6; ++it) {
        int f = it * 256 + tid;
        int row = f >> 5, c4 = f & 31;
        et4[row][c4] = *reinterpret_cast<const float4*>(eb + (size_t)row * (TT * CC) + c4 * 4);
    }
    #pragma unroll
    for (int it = 0; it < 2; ++it) {
        int f = it * 256 + tid;
        int row = f >> 5, c4 = f & 31;
        const float* src = (row < 4)
            ? (xA + ((size_t)(b * NN + third * 4 + row) * TT + t) * CC)
            : (xB + ((size_t)(b * NN + (row - 4)) * TT + t) * CC);
        xab4[row][c4] = *reinterpret_cast<const float4*>(src + c4 * 4);
    }
    __syncthreads();
    int lane = tid & 63, wid = tid >> 6;
    int l15 = lane & 15, l4 = lane >> 4;
    v8s bfr[2][4];
    #pragma unroll
    for (int nt2 = 0; nt2 < 2; ++nt2) {
        int col = (wid * 2 + nt2) * 16 + l15;
        #pragma unroll
        for (int kk = 0; kk < 4; ++kk)
            bfr[nt2][kk] = *reinterpret_cast<const v8s*>(Ebf + col * 128 + kk * 32 + l4 * 8);
    }
    v4f acc[3][2] = {};
    #pragma unroll
    for (int kk = 0; kk < 4; ++kk) {
        #pragma unroll
        for (int mt = 0; mt < 3; ++mt) {
            v8s a = frag_from_f32(&et4[mt * 16 + l15][kk * 8 + l4 * 2]);
            acc[mt][0] = __builtin_amdgcn_mfma_f32_16x16x32_bf16(a, bfr[0][kk], acc[mt][0], 0, 0, 0);
            acc[mt][1] = __builtin_amdgcn_mfma_f32_16x16x32_bf16(a, bfr[1][kk], acc[mt][1], 0, 0, 0);
        }
    }
    const float* xabf = reinterpret_cast<const float*>(xab4);
    #pragma unroll
    for (int mt = 0; mt < 3; ++mt) {
        #pragma unroll
        for (int reg = 0; reg < 4; ++reg) {
            int r = mt * 16 + l4 * 4 + reg;
            int il = r / 12, jl = r - il * 12;
            float s = 0.f, q = 0.f;
            #pragma unroll
            for (int nt2 = 0; nt2 < 2; ++nt2) {
                int col = (wid * 2 + nt2) * 16 + l15;
                float v = acc[mt][nt2][reg] + xabf[il * 132 + col] + xabf[(4 + jl) * 132 + col];
                s += v; q += v * v;
            }
            #pragma unroll
            for (int off = 1; off < 16; off <<= 1) { s += __shfl_xor(s, off); q += __shfl_xor(q, off); }
            if (l15 == 0) { atomicAdd(&srow[r], s); atomicAdd(&qrow[r], q); }
        }
    }
    __syncthreads();
    if (tid < 48) {
        epart[(size_t)bid * 96 + tid * 2 + 0] = srow[tid];
        epart[(size_t)bid * 96 + tid * 2 + 1] = qrow[tid];
    }
}

// ---------------- reduce edge stats -> scale/shift ----------------
__global__ __launch_bounds__(256) void kRede(
    const float* __restrict__ epart, const float* __restrict__ g,
    const float* __restrict__ be, float* __restrict__ estats)
{
    int e = blockIdx.x;              // 0..143
    int third = e / 48, le = e % 48;
    float s = 0.f, q = 0.f;
    for (int bt = threadIdx.x; bt < 2048; bt += 256) {
        const float* p = epart + ((size_t)(bt * 3 + third) * 96 + le * 2);
        s += p[0]; q += p[1];
    }
    __shared__ float ss[4], qq[4];
    #pragma unroll
    for (int off = 32; off >= 1; off >>= 1) { s += __shfl_down(s, off); q += __shfl_down(q, off); }
    int wid = threadIdx.x >> 6;
    if ((threadIdx.x & 63) == 0) { ss[wid] = s; qq[wid] = q; }
    __syncthreads();
    if (threadIdx.x == 0) {
        s = ss[0] + ss[1] + ss[2] + ss[3];
        q = qq[0] + qq[1] + qq[2] + qq[3];
        const float M = 262144.f;    // B*T*C
        float mean = s / M;
        float var = q / M - mean * mean;
        float sc = g[e] * rsqrtf(var + 1e-5f);
        estats[e * 2] = sc;
        estats[e * 2 + 1] = be[e] - mean * sc;
    }
}

// ---------------- C: edge update + softmax + agg ----------------
__global__ __launch_bounds__(256) void kC(
    const float* edge_in, float* edge_out,
    const float* __restrict__ xA, const float* __restrict__ xB,
    const float* __restrict__ xV, const float* __restrict__ xU,
    const unsigned short* __restrict__ Ebf, const float* __restrict__ estats,
    float* __restrict__ yout, float* __restrict__ npart)
{
    __shared__ float4 et4[48][33];
    __shared__ float4 xab4[28][33];
    __shared__ float scs[48], shs[48];
    __shared__ float ns[4], nq[4];
    int tid = threadIdx.x;
    int bid = blockIdx.x;
    int third = bid % 3; int bt = bid / 3;
    int b = bt >> 7, t = bt & 127;
    if (tid < 48) { scs[tid] = estats[(third * 48 + tid) * 2]; shs[tid] = estats[(third * 48 + tid) * 2 + 1]; }
    if (tid < 4) { ns[tid] = 0.f; nq[tid] = 0.f; }
    const float* eb = edge_in + ((size_t)(b * NE + third * 48) * TT + t) * CC;
    #pragma unroll
    for (int it = 0; it < 6; ++it) {
        int f = it * 256 + tid;
        int row = f >> 5, c4 = f & 31;
        et4[row][c4] = *reinterpret_cast<const float4*>(eb + (size_t)row * (TT * CC) + c4 * 4);
    }
    #pragma unroll
    for (int it = 0; it < 4; ++it) {
        int f = it * 256 + tid;
        if (f < 896) {
            int row = f >> 5, c4 = f & 31;
            const float* src;
            if (row < 4)       src = xA + ((size_t)(b * NN + third * 4 + row) * TT + t) * CC;
            else if (row < 16) src = xB + ((size_t)(b * NN + (row - 4)) * TT + t) * CC;
            else               src = xV + ((size_t)(b * NN + (row - 16)) * TT + t) * CC;
            xab4[row][c4] = *reinterpret_cast<const float4*>(src + c4 * 4);
        }
    }
    __syncthreads();
    int lane = tid & 63, wid = tid >> 6;
    int l15 = lane & 15, l4 = lane >> 4;
    v8s bfr[2][4];
    #pragma unroll
    for (int nt2 = 0; nt2 < 2; ++nt2) {
        int col = (wid * 2 + nt2) * 16 + l15;
        #pragma unroll
        for (int kk = 0; kk < 4; ++kk)
            bfr[nt2][kk] = *reinterpret_cast<const v8s*>(Ebf + col * 128 + kk * 32 + l4 * 8);
    }
    v4f acc[3][2] = {};
    #pragma unroll
    for (int kk = 0; kk < 4; ++kk) {
        #pragma unroll
        for (int mt = 0; mt < 3; ++mt) {
            v8s a = frag_from_f32(&et4[mt * 16 + l15][kk * 8 + l4 * 2]);
            acc[mt][0] = __builtin_amdgcn_mfma_f32_16x16x32_bf16(a, bfr[0][kk], acc[mt][0], 0, 0, 0);
            acc[mt][1] = __builtin_amdgcn_mfma_f32_16x16x32_bf16(a, bfr[1][kk], acc[mt][1], 0, 0, 0);
        }
    }
    __syncthreads();   // all LDS frag reads done before overwrite
    float* etf = reinterpret_cast<float*>(et4);
    const float* xabf = reinterpret_cast<const float*>(xab4);
    #pragma unroll
    for (int mt = 0; mt < 3; ++mt) {
        #pragma unroll
        for (int reg = 0; reg < 4; ++reg) {
            int r = mt * 16 + l4 * 4 + reg;
            int il = r / 12, jl = r - il * 12;
            int eg = third * 48 + r;
            float scv = scs[r], shv = shs[r];
            #pragma unroll
            for (int nt2 = 0; nt2 < 2; ++nt2) {
                int col = (wid * 2 + nt2) * 16 + l15;
                float v = acc[mt][nt2][reg] + xabf[il * 132 + col] + xabf[(4 + jl) * 132 + col];
                float bn = scv * v + shv;
                float en = etf[r * 132 + col] + fmaxf(bn, 0.f);
                etf[r * 132 + col] = en;
                edge_out[((size_t)(b * NE + eg) * TT + t) * CC + col] = en;
            }
        }
    }
    __syncthreads();
    #pragma unroll
    for (int ph = 0; ph < 2; ++ph) {
        int unit = tid + ph * 256;       // 512 units = 4 i_loc * 128 c
        int il = unit >> 7, c = unit & 127;
        float den = 0.f, ag = 0.f;
        #pragma unroll
        for (int j = 0; j < 12; ++j) {
            float sv = etf[(il * 12 + j) * 132 + c];
            float sg = 1.f / (1.f + __expf(-sv));
            float ev = __expf(sg);
            den += ev;
            ag += ev * xabf[(16 + j) * 132 + c];
        }
        float agg = ag / (den * 12.f);
        int i = third * 4 + il;
        size_t xa = ((size_t)(b * NN + i) * TT + t) * CC + c;
        float yv = xU[xa] + agg;
        yout[xa] = yv;
        float s1 = yv, s2 = yv * yv;
        #pragma unroll
        for (int off = 1; off < 64; off <<= 1) { s1 += __shfl_xor(s1, off); s2 += __shfl_xor(s2, off); }
        if (lane == 0) { atomicAdd(&ns[il], s1); atomicAdd(&nq[il], s2); }
    }
    __syncthreads();
    if (tid < 4) {
        npart[(size_t)bid * 8 + tid * 2 + 0] = ns[tid];
        npart[(size_t)bid * 8 + tid * 2 + 1] = nq[tid];
    }
}

// ---------------- reduce node stats ----------------
__global__ __launch_bounds__(256) void kRedn(
    const float* __restrict__ npart, const float* __restrict__ g,
    const float* __restrict__ be, float* __restrict__ nstats)
{
    int n = blockIdx.x;             // 0..11
    int third = n >> 2, il = n & 3;
    float s = 0.f, q = 0.f;
    for (int bt = threadIdx.x; bt < 2048; bt += 256) {
        const float* p = npart + ((size_t)(bt * 3 + third) * 8 + il * 2);
        s += p[0]; q += p[1];
    }
    __shared__ float ss[4], qq[4];
    #pragma unroll
    for (int off = 32; off >= 1; off >>= 1) { s += __shfl_down(s, off); q += __shfl_down(q, off); }
    int wid = threadIdx.x >> 6;
    if ((threadIdx.x & 63) == 0) { ss[wid] = s; qq[wid] = q; }
    __syncthreads();
    if (threadIdx.x == 0) {
        s = ss[0] + ss[1] + ss[2] + ss[3];
        q = qq[0] + qq[1] + qq[2] + qq[3];
        const float M = 262144.f;   // B*T*C
        float mean = s / M;
        float var = q / M - mean * mean;
        float sc = g[n] * rsqrtf(var + 1e-5f);
        nstats[n * 2] = sc;
        nstats[n * 2 + 1] = be[n] - mean * sc;
    }
}

// ---------------- E: node BN + residual + relu ----------------
__global__ __launch_bounds__(256) void kE(
    const float* xres, const float* __restrict__ yin,
    const float* __restrict__ nstats, float* xout)
{
    int idx4 = blockIdx.x * 256 + threadIdx.x;     // 786432 float4s
    size_t base = (size_t)idx4 * 4;
    int n = (int)((base >> 14) % 12);
    float scv = nstats[n * 2], shv = nstats[n * 2 + 1];
    float4 xv = *reinterpret_cast<const float4*>(xres + base);
    float4 yv = *reinterpret_cast<const float4*>(yin + base);
    float4 o;
    o.x = fmaxf(xv.x + scv * yv.x + shv, 0.f);
    o.y = fmaxf(xv.y + scv * yv.y + shv, 0.f);
    o.z = fmaxf(xv.z + scv * yv.z + shv, 0.f);
    o.w = fmaxf(xv.w + scv * yv.w + shv, 0.f);
    *reinterpret_cast<float4*>(xout + base) = o;
}

extern "C" void kernel_launch(void* const* d_in, const int* in_sizes, int n_in,
                              void* d_out, int out_size, void* d_ws, size_t ws_size,
                              hipStream_t stream)
{
    const float* x0 = (const float*)d_in[0];
    const float* e0 = (const float*)d_in[1];
    const float* W[10];
    for (int i = 0; i < 10; ++i) W[i] = (const float*)d_in[2 + i];
    const float* ge1 = (const float*)d_in[12];
    const float* be1 = (const float*)d_in[13];
    const float* gv1 = (const float*)d_in[14];
    const float* bv1 = (const float*)d_in[15];
    const float* ge2 = (const float*)d_in[16];
    const float* be2 = (const float*)d_in[17];
    const float* gv2 = (const float*)d_in[18];
    const float* bv2 = (const float*)d_in[19];

    const size_t SZX = (size_t)BB * NN * TT * CC;   // 3145728
    float* out_x = (float*)d_out;
    float* out_e = out_x + SZX;

    float* ws = (float*)d_ws;
    float* xA = ws;
    float* xB = ws + SZX;
    float* xV = ws + 2 * SZX;
    float* xU = ws + 3 * SZX;
    float* yb = ws + 4 * SZX;
    float* epart  = ws + 5 * SZX;          // 6144*96
    float* estats = epart + 589824;        // 288
    float* npart  = estats + 288;          // 6144*8
    float* nstats = npart + 49152;         // 24
    unsigned short* wb = (unsigned short*)(nstats + 24);   // 10*16384 bf16

    float* x1 = out_x;   // layer-1 x output scratch (overwritten by layer 2)

    kW<<<640, 256, 0, stream>>>(W[0], W[1], W[2], W[3], W[4], W[5], W[6], W[7], W[8], W[9], wb);

    // ---- layer 1 ----
    kP<<<384, 256, 0, stream>>>(x0, wb, 0, 1, 4, 3, xA, xB, xV, xU);
    kA<<<6144, 256, 0, stream>>>(e0, xA, xB, wb + 2 * 16384, epart);
    kRede<<<144, 256, 0, stream>>>(epart, ge1, be1, estats);
    kC<<<6144, 256, 0, stream>>>(e0, out_e, xA, xB, xV, xU, wb + 2 * 16384, estats, yb, npart);
    kRedn<<<12, 256, 0, stream>>>(npart, gv1, bv1, nstats);
    kE<<<3072, 256, 0, stream>>>(x0, yb, nstats, x1);

    // ---- layer 2 ----
    kP<<<384, 256, 0, stream>>>(x1, wb, 5, 6, 9, 8, xA, xB, xV, xU);
    kA<<<6144, 256, 0, stream>>>(out_e, xA, xB, wb + 7 * 16384, epart);
    kRede<<<144, 256, 0, stream>>>(epart, ge2, be2, estats);
    kC<<<6144, 256, 0, stream>>>(out_e, out_e, xA, xB, xV, xU, wb + 7 * 16384, estats, yb, npart);
    kRedn<<<12, 256, 0, stream>>>(npart, gv2, bv2, nstats);
    kE<<<3072, 256, 0, stream>>>(x1, yb, nstats, out_x);
}

// Round 2
// 310.062 us; speedup vs baseline: 1.2087x; 1.2087x over previous
//
#include <hip/hip_runtime.h>
#include <hip/hip_bf16.h>

#define BB 16
#define NN 12
#define NE 144
#define TT 128
#define CC 128

typedef __attribute__((ext_vector_type(8))) short v8s;   // 8 x bf16
typedef __attribute__((ext_vector_type(4))) short v4s;   // 4 x bf16
typedef __attribute__((ext_vector_type(4))) float v4f;   // mfma accumulator

__device__ __forceinline__ short f2bf(float f) {
    unsigned u = __float_as_uint(f);
    u += 0x7fffu + ((u >> 16) & 1u);        // RNE
    return (short)(u >> 16);
}
__device__ __forceinline__ float bf2f(unsigned short u) {
    return __uint_as_float(((unsigned)u) << 16);
}
__device__ __forceinline__ v4s f4_to_bf4(float4 a) {
    v4s r; r[0] = f2bf(a.x); r[1] = f2bf(a.y); r[2] = f2bf(a.z); r[3] = f2bf(a.w); return r;
}
__device__ __forceinline__ float4 bf4_to_f4(v4s a) {
    float4 r;
    r.x = bf2f((unsigned short)a[0]); r.y = bf2f((unsigned short)a[1]);
    r.z = bf2f((unsigned short)a[2]); r.w = bf2f((unsigned short)a[3]);
    return r;
}
// short index of bf16 row (b,e,t) inside the f32 out_e region (slot layout:
// first 256B of each 512B f32 row slot). Exactly one block owns each row.
__device__ __forceinline__ size_t eslot(int b, int e, int t) {
    return ((((size_t)b * NE + e) * TT + t) * CC) * 2;
}

// ---------------- weights -> bf16 ----------------
__global__ __launch_bounds__(256) void kW(
    const float* A1, const float* B1, const float* E1, const float* U1, const float* V1,
    const float* A2, const float* B2, const float* E2, const float* U2, const float* V2,
    unsigned short* wb)
{
    int idx = blockIdx.x * 256 + threadIdx.x;   // 10*16384
    int w = idx >> 14, r = idx & 16383;
    const float* s;
    switch (w) {
        case 0: s = A1; break; case 1: s = B1; break; case 2: s = E1; break;
        case 3: s = U1; break; case 4: s = V1; break; case 5: s = A2; break;
        case 6: s = B2; break; case 7: s = E2; break; case 8: s = U2; break;
        default: s = V2; break;
    }
    wb[idx] = (unsigned short)f2bf(s[r]);
}

// ---------------- P: x @ {A,B,V,U}^T  -> bf16 outputs ----------------
__global__ __launch_bounds__(256) void kP(
    const float* __restrict__ x, const unsigned short* __restrict__ wb,
    int sA, int sB, int sV, int sU,
    unsigned short* __restrict__ oA, unsigned short* __restrict__ oB,
    unsigned short* __restrict__ oV, unsigned short* __restrict__ oU)
{
    __shared__ unsigned short xt[64][136];
    int tid = threadIdx.x;
    int m0 = blockIdx.x * 64;
    #pragma unroll
    for (int it = 0; it < 8; ++it) {
        int f = it * 256 + tid;
        int row = f >> 5, c4 = f & 31;
        float4 v = *reinterpret_cast<const float4*>(x + (size_t)m0 * 128 + (size_t)f * 4);
        *reinterpret_cast<v4s*>(&xt[row][c4 * 4]) = f4_to_bf4(v);
    }
    __syncthreads();
    int lane = tid & 63, wid = tid >> 6;
    int l15 = lane & 15, l4 = lane >> 4;

    const unsigned short* Ws[4] = { wb + (size_t)sA * 16384, wb + (size_t)sB * 16384,
                                    wb + (size_t)sV * 16384, wb + (size_t)sU * 16384 };
    unsigned short* Os[4] = { oA, oB, oV, oU };

    #pragma unroll
    for (int w = 0; w < 4; ++w) {
        const unsigned short* W = Ws[w];
        unsigned short* out = Os[w];
        v8s bfr[2][4];
        #pragma unroll
        for (int nt2 = 0; nt2 < 2; ++nt2) {
            int col = (wid * 2 + nt2) * 16 + l15;
            #pragma unroll
            for (int kk = 0; kk < 4; ++kk)
                bfr[nt2][kk] = *reinterpret_cast<const v8s*>(W + col * 128 + kk * 32 + l4 * 8);
        }
        v4f acc[4][2] = {};
        #pragma unroll
        for (int kk = 0; kk < 4; ++kk) {
            #pragma unroll
            for (int mt = 0; mt < 4; ++mt) {
                v8s a = *reinterpret_cast<const v8s*>(&xt[mt * 16 + l15][kk * 32 + l4 * 8]);
                acc[mt][0] = __builtin_amdgcn_mfma_f32_16x16x32_bf16(a, bfr[0][kk], acc[mt][0], 0, 0, 0);
                acc[mt][1] = __builtin_amdgcn_mfma_f32_16x16x32_bf16(a, bfr[1][kk], acc[mt][1], 0, 0, 0);
            }
        }
        #pragma unroll
        for (int mt = 0; mt < 4; ++mt) {
            #pragma unroll
            for (int nt2 = 0; nt2 < 2; ++nt2) {
                int col = (wid * 2 + nt2) * 16 + l15;
                #pragma unroll
                for (int reg = 0; reg < 4; ++reg) {
                    int rowg = m0 + mt * 16 + l4 * 4 + reg;
                    out[(size_t)rowg * 128 + col] = (unsigned short)f2bf(acc[mt][nt2][reg]);
                }
            }
        }
    }
}

// ---------------- A: edge_upd stats (+ optional f32->bf16 edge convert) ----------------
template<bool IN_F32>
__global__ __launch_bounds__(256) void kA(
    const float* __restrict__ ef32, const unsigned short* ebf,
    unsigned short* ebout,
    const unsigned short* __restrict__ xA, const unsigned short* __restrict__ xB,
    const unsigned short* __restrict__ Ebf, float* __restrict__ epart)
{
    __shared__ unsigned short ebt[48][136];
    __shared__ float4 xab4[16][33];
    __shared__ float srow[48], qrow[48];
    int tid = threadIdx.x;
    int bid = blockIdx.x;
    int third = bid % 3; int bt = bid / 3;
    int b = bt >> 7, t = bt & 127;
    if (tid < 48) { srow[tid] = 0.f; qrow[tid] = 0.f; }

    if constexpr (IN_F32) {
        const float* eb = ef32 + (((size_t)(b * NE + third * 48) * TT) + t) * CC;
        #pragma unroll
        for (int it = 0; it < 6; ++it) {
            int f = it * 256 + tid;
            int row = f >> 5, c4 = f & 31;
            float4 v = *reinterpret_cast<const float4*>(eb + (size_t)row * (TT * CC) + c4 * 4);
            *reinterpret_cast<v4s*>(&ebt[row][c4 * 4]) = f4_to_bf4(v);
        }
    } else {
        #pragma unroll
        for (int it = 0; it < 3; ++it) {
            int f = it * 256 + tid;
            int row = f >> 4, c8 = f & 15;
            *reinterpret_cast<v8s*>(&ebt[row][c8 * 8]) =
                *reinterpret_cast<const v8s*>(ebf + eslot(b, third * 48 + row, t) + c8 * 8);
        }
    }
    #pragma unroll
    for (int it = 0; it < 2; ++it) {
        int f = it * 256 + tid;
        int row = f >> 5, c4 = f & 31;
        const unsigned short* src = (row < 4)
            ? (xA + (((size_t)(b * NN + third * 4 + row) * TT) + t) * CC)
            : (xB + (((size_t)(b * NN + (row - 4)) * TT) + t) * CC);
        v4s v = *reinterpret_cast<const v4s*>(src + c4 * 4);
        xab4[row][c4] = bf4_to_f4(v);
    }
    __syncthreads();
    if constexpr (IN_F32) {    // fused e0 -> bf16 global convert for kC1/kA2/kC2
        #pragma unroll
        for (int it = 0; it < 3; ++it) {
            int f = it * 256 + tid;
            int row = f >> 4, c8 = f & 15;
            *reinterpret_cast<v8s*>(ebout + eslot(b, third * 48 + row, t) + c8 * 8) =
                *reinterpret_cast<const v8s*>(&ebt[row][c8 * 8]);
        }
    }
    int lane = tid & 63, wid = tid >> 6;
    int l15 = lane & 15, l4 = lane >> 4;
    v8s bfr[2][4];
    #pragma unroll
    for (int nt2 = 0; nt2 < 2; ++nt2) {
        int col = (wid * 2 + nt2) * 16 + l15;
        #pragma unroll
        for (int kk = 0; kk < 4; ++kk)
            bfr[nt2][kk] = *reinterpret_cast<const v8s*>(Ebf + col * 128 + kk * 32 + l4 * 8);
    }
    v4f acc[3][2] = {};
    #pragma unroll
    for (int kk = 0; kk < 4; ++kk) {
        #pragma unroll
        for (int mt = 0; mt < 3; ++mt) {
            v8s a = *reinterpret_cast<const v8s*>(&ebt[mt * 16 + l15][kk * 32 + l4 * 8]);
            acc[mt][0] = __builtin_amdgcn_mfma_f32_16x16x32_bf16(a, bfr[0][kk], acc[mt][0], 0, 0, 0);
            acc[mt][1] = __builtin_amdgcn_mfma_f32_16x16x32_bf16(a, bfr[1][kk], acc[mt][1], 0, 0, 0);
        }
    }
    const float* xabf = reinterpret_cast<const float*>(xab4);
    #pragma unroll
    for (int mt = 0; mt < 3; ++mt) {
        #pragma unroll
        for (int reg = 0; reg < 4; ++reg) {
            int r = mt * 16 + l4 * 4 + reg;
            int il = r / 12, jl = r - il * 12;
            float s = 0.f, q = 0.f;
            #pragma unroll
            for (int nt2 = 0; nt2 < 2; ++nt2) {
                int col = (wid * 2 + nt2) * 16 + l15;
                float v = acc[mt][nt2][reg] + xabf[il * 132 + col] + xabf[(4 + jl) * 132 + col];
                s += v; q += v * v;
            }
            #pragma unroll
            for (int off = 1; off < 16; off <<= 1) { s += __shfl_xor(s, off); q += __shfl_xor(q, off); }
            if (l15 == 0) { atomicAdd(&srow[r], s); atomicAdd(&qrow[r], q); }
        }
    }
    __syncthreads();
    if (tid < 48) {
        epart[(size_t)bid * 96 + tid * 2 + 0] = srow[tid];
        epart[(size_t)bid * 96 + tid * 2 + 1] = qrow[tid];
    }
}

// ---------------- reduce edge stats -> scale/shift ----------------
__global__ __launch_bounds__(256) void kRede(
    const float* __restrict__ epart, const float* __restrict__ g,
    const float* __restrict__ be, float* __restrict__ estats)
{
    int e = blockIdx.x;              // 0..143
    int third = e / 48, le = e % 48;
    float s = 0.f, q = 0.f;
    for (int bt = threadIdx.x; bt < 2048; bt += 256) {
        const float* p = epart + ((size_t)(bt * 3 + third) * 96 + le * 2);
        s += p[0]; q += p[1];
    }
    __shared__ float ss[4], qq[4];
    #pragma unroll
    for (int off = 32; off >= 1; off >>= 1) { s += __shfl_down(s, off); q += __shfl_down(q, off); }
    int wid = threadIdx.x >> 6;
    if ((threadIdx.x & 63) == 0) { ss[wid] = s; qq[wid] = q; }
    __syncthreads();
    if (threadIdx.x == 0) {
        s = ss[0] + ss[1] + ss[2] + ss[3];
        q = qq[0] + qq[1] + qq[2] + qq[3];
        const float M = 262144.f;    // B*T*C
        float mean = s / M;
        float var = q / M - mean * mean;
        float sc = g[e] * rsqrtf(var + 1e-5f);
        estats[e * 2] = sc;
        estats[e * 2 + 1] = be[e] - mean * sc;
    }
}

// ---------------- C: edge update + softmax + agg ----------------
template<bool OUT_F32>
__global__ __launch_bounds__(256) void kC(
    const unsigned short* ebuf,                // bf16 slot layout (in)
    unsigned short* ebout_bf,                  // == ebuf, bf16 write-back (L1)
    float* edge_out_f32,                       // f32 final (L2); aliases ebuf slots
    const unsigned short* __restrict__ xA, const unsigned short* __restrict__ xB,
    const unsigned short* __restrict__ xV, const unsigned short* __restrict__ xU,
    const unsigned short* __restrict__ Ebf, const float* __restrict__ estats,
    unsigned short* __restrict__ yout, float* __restrict__ npart)
{
    __shared__ unsigned short ebt[48][136];
    __shared__ float4 xab4[28][33];
    __shared__ float scs[48], shs[48];
    __shared__ float ns[4], nq[4];
    int tid = threadIdx.x;
    int bid = blockIdx.x;
    int third = bid % 3; int bt = bid / 3;
    int b = bt >> 7, t = bt & 127;
    if (tid < 48) { scs[tid] = estats[(third * 48 + tid) * 2]; shs[tid] = estats[(third * 48 + tid) * 2 + 1]; }
    if (tid < 4) { ns[tid] = 0.f; nq[tid] = 0.f; }
    #pragma unroll
    for (int it = 0; it < 3; ++it) {
        int f = it * 256 + tid;
        int row = f >> 4, c8 = f & 15;
        *reinterpret_cast<v8s*>(&ebt[row][c8 * 8]) =
            *reinterpret_cast<const v8s*>(ebuf + eslot(b, third * 48 + row, t) + c8 * 8);
    }
    #pragma unroll
    for (int it = 0; it < 4; ++it) {
        int f = it * 256 + tid;
        if (f < 896) {
            int row = f >> 5, c4 = f & 31;
            const unsigned short* src;
            if (row < 4)       src = xA + (((size_t)(b * NN + third * 4 + row) * TT) + t) * CC;
            else if (row < 16) src = xB + (((size_t)(b * NN + (row - 4)) * TT) + t) * CC;
            else               src = xV + (((size_t)(b * NN + (row - 16)) * TT) + t) * CC;
            v4s v = *reinterpret_cast<const v4s*>(src + c4 * 4);
            xab4[row][c4] = bf4_to_f4(v);
        }
    }
    __syncthreads();
    int lane = tid & 63, wid = tid >> 6;
    int l15 = lane & 15, l4 = lane >> 4;
    v8s bfr[2][4];
    #pragma unroll
    for (int nt2 = 0; nt2 < 2; ++nt2) {
        int col = (wid * 2 + nt2) * 16 + l15;
        #pragma unroll
        for (int kk = 0; kk < 4; ++kk)
            bfr[nt2][kk] = *reinterpret_cast<const v8s*>(Ebf + col * 128 + kk * 32 + l4 * 8);
    }
    v4f acc[3][2] = {};
    #pragma unroll
    for (int kk = 0; kk < 4; ++kk) {
        #pragma unroll
        for (int mt = 0; mt < 3; ++mt) {
            v8s a = *reinterpret_cast<const v8s*>(&ebt[mt * 16 + l15][kk * 32 + l4 * 8]);
            acc[mt][0] = __builtin_amdgcn_mfma_f32_16x16x32_bf16(a, bfr[0][kk], acc[mt][0], 0, 0, 0);
            acc[mt][1] = __builtin_amdgcn_mfma_f32_16x16x32_bf16(a, bfr[1][kk], acc[mt][1], 0, 0, 0);
        }
    }
    __syncthreads();   // all LDS frag reads done before overwrite
    const float* xabf = reinterpret_cast<const float*>(xab4);
    #pragma unroll
    for (int mt = 0; mt < 3; ++mt) {
        #pragma unroll
        for (int reg = 0; reg < 4; ++reg) {
            int r = mt * 16 + l4 * 4 + reg;
            int il = r / 12, jl = r - il * 12;
            int eg = third * 48 + r;
            float scv = scs[r], shv = shs[r];
            #pragma unroll
            for (int nt2 = 0; nt2 < 2; ++nt2) {
                int col = (wid * 2 + nt2) * 16 + l15;
                float v = acc[mt][nt2][reg] + xabf[il * 132 + col] + xabf[(4 + jl) * 132 + col];
                float bn = scv * v + shv;
                float en = bf2f(ebt[r][col]) + fmaxf(bn, 0.f);
                ebt[r][col] = (unsigned short)f2bf(en);
                if constexpr (OUT_F32)
                    edge_out_f32[((size_t)(b * NE + eg) * TT + t) * CC + col] = en;
            }
        }
    }
    __syncthreads();
    if constexpr (!OUT_F32) {   // write bf16 tile back to its own slots
        #pragma unroll
        for (int it = 0; it < 3; ++it) {
            int f = it * 256 + tid;
            int row = f >> 4, c8 = f & 15;
            *reinterpret_cast<v8s*>(ebout_bf + eslot(b, third * 48 + row, t) + c8 * 8) =
                *reinterpret_cast<const v8s*>(&ebt[row][c8 * 8]);
        }
    }
    #pragma unroll
    for (int ph = 0; ph < 2; ++ph) {
        int unit = tid + ph * 256;       // 512 units = 4 i_loc * 128 c
        int il = unit >> 7, c = unit & 127;
        float den = 0.f, ag = 0.f;
        #pragma unroll
        for (int j = 0; j < 12; ++j) {
            float sv = bf2f(ebt[il * 12 + j][c]);
            float sg = 1.f / (1.f + __expf(-sv));
            float ev = __expf(sg);
            den += ev;
            ag += ev * xabf[(16 + j) * 132 + c];
        }
        float agg = ag / (den * 12.f);
        int i = third * 4 + il;
        size_t xa = (((size_t)(b * NN + i) * TT) + t) * CC + c;
        float yv = bf2f(xU[xa]) + agg;
        unsigned short us = (unsigned short)f2bf(yv);
        yout[xa] = us;
        float yr = bf2f(us);
        float s1 = yr, s2 = yr * yr;
        #pragma unroll
        for (int off = 1; off < 64; off <<= 1) { s1 += __shfl_xor(s1, off); s2 += __shfl_xor(s2, off); }
        if (lane == 0) { atomicAdd(&ns[il], s1); atomicAdd(&nq[il], s2); }
    }
    __syncthreads();
    if (tid < 4) {
        npart[(size_t)bid * 8 + tid * 2 + 0] = ns[tid];
        npart[(size_t)bid * 8 + tid * 2 + 1] = nq[tid];
    }
}

// ---------------- reduce node stats ----------------
__global__ __launch_bounds__(256) void kRedn(
    const float* __restrict__ npart, const float* __restrict__ g,
    const float* __restrict__ be, float* __restrict__ nstats)
{
    int n = blockIdx.x;             // 0..11
    int third = n >> 2, il = n & 3;
    float s = 0.f, q = 0.f;
    for (int bt = threadIdx.x; bt < 2048; bt += 256) {
        const float* p = npart + ((size_t)(bt * 3 + third) * 8 + il * 2);
        s += p[0]; q += p[1];
    }
    __shared__ float ss[4], qq[4];
    #pragma unroll
    for (int off = 32; off >= 1; off >>= 1) { s += __shfl_down(s, off); q += __shfl_down(q, off); }
    int wid = threadIdx.x >> 6;
    if ((threadIdx.x & 63) == 0) { ss[wid] = s; qq[wid] = q; }
    __syncthreads();
    if (threadIdx.x == 0) {
        s = ss[0] + ss[1] + ss[2] + ss[3];
        q = qq[0] + qq[1] + qq[2] + qq[3];
        const float M = 262144.f;   // B*T*C
        float mean = s / M;
        float var = q / M - mean * mean;
        float sc = g[n] * rsqrtf(var + 1e-5f);
        nstats[n * 2] = sc;
        nstats[n * 2 + 1] = be[n] - mean * sc;
    }
}

// ---------------- E: node BN + residual + relu ----------------
__global__ __launch_bounds__(256) void kE(
    const float* xres, const unsigned short* __restrict__ yin,
    const float* __restrict__ nstats, float* xout)
{
    int idx4 = blockIdx.x * 256 + threadIdx.x;     // 786432 float4s
    size_t base = (size_t)idx4 * 4;
    int n = (int)((base >> 14) % 12);
    float scv = nstats[n * 2], shv = nstats[n * 2 + 1];
    float4 xv = *reinterpret_cast<const float4*>(xres + base);
    float4 yv = bf4_to_f4(*reinterpret_cast<const v4s*>(yin + base));
    float4 o;
    o.x = fmaxf(xv.x + scv * yv.x + shv, 0.f);
    o.y = fmaxf(xv.y + scv * yv.y + shv, 0.f);
    o.z = fmaxf(xv.z + scv * yv.z + shv, 0.f);
    o.w = fmaxf(xv.w + scv * yv.w + shv, 0.f);
    *reinterpret_cast<float4*>(xout + base) = o;
}

extern "C" void kernel_launch(void* const* d_in, const int* in_sizes, int n_in,
                              void* d_out, int out_size, void* d_ws, size_t ws_size,
                              hipStream_t stream)
{
    const float* x0 = (const float*)d_in[0];
    const float* e0 = (const float*)d_in[1];
    const float* W[10];
    for (int i = 0; i < 10; ++i) W[i] = (const float*)d_in[2 + i];
    const float* ge1 = (const float*)d_in[12];
    const float* be1 = (const float*)d_in[13];
    const float* gv1 = (const float*)d_in[14];
    const float* bv1 = (const float*)d_in[15];
    const float* ge2 = (const float*)d_in[16];
    const float* be2 = (const float*)d_in[17];
    const float* gv2 = (const float*)d_in[18];
    const float* bv2 = (const float*)d_in[19];

    const size_t SZX = (size_t)BB * NN * TT * CC;   // 3145728
    float* out_x = (float*)d_out;
    float* out_e = out_x + SZX;
    unsigned short* ebuf = (unsigned short*)out_e;  // bf16 slot overlay of out_e

    unsigned short* ws16 = (unsigned short*)d_ws;
    unsigned short* xA = ws16;
    unsigned short* xB = ws16 + SZX;
    unsigned short* xV = ws16 + 2 * SZX;
    unsigned short* xU = ws16 + 3 * SZX;
    unsigned short* yb = ws16 + 4 * SZX;
    float* fpart  = (float*)(ws16 + 5 * SZX);
    float* epart  = fpart;                 // 6144*96
    float* estats = epart + 589824;        // 288
    float* npart  = estats + 288;          // 6144*8
    float* nstats = npart + 49152;         // 24
    unsigned short* wb = (unsigned short*)(nstats + 24);   // 10*16384 bf16

    float* x1 = out_x;   // layer-1 x output scratch (rewritten in-place by kE2)

    kW<<<640, 256, 0, stream>>>(W[0], W[1], W[2], W[3], W[4], W[5], W[6], W[7], W[8], W[9], wb);

    // ---- layer 1 ----
    kP<<<384, 256, 0, stream>>>(x0, wb, 0, 1, 4, 3, xA, xB, xV, xU);
    kA<true><<<6144, 256, 0, stream>>>(e0, nullptr, ebuf, xA, xB, wb + 2 * 16384, epart);
    kRede<<<144, 256, 0, stream>>>(epart, ge1, be1, estats);
    kC<false><<<6144, 256, 0, stream>>>(ebuf, ebuf, nullptr, xA, xB, xV, xU,
                                        wb + 2 * 16384, estats, yb, npart);
    kRedn<<<12, 256, 0, stream>>>(npart, gv1, bv1, nstats);
    kE<<<3072, 256, 0, stream>>>(x0, yb, nstats, x1);

    // ---- layer 2 ----
    kP<<<384, 256, 0, stream>>>(x1, wb, 5, 6, 9, 8, xA, xB, xV, xU);
    kA<false><<<6144, 256, 0, stream>>>(nullptr, ebuf, nullptr, xA, xB, wb + 7 * 16384, epart);
    kRede<<<144, 256, 0, stream>>>(epart, ge2, be2, estats);
    kC<true><<<6144, 256, 0, stream>>>(ebuf, nullptr, out_e, xA, xB, xV, xU,
                                       wb + 7 * 16384, estats, yb, npart);
    kRedn<<<12, 256, 0, stream>>>(npart, gv2, bv2, nstats);
    kE<<<3072, 256, 0, stream>>>(x1, yb, nstats, out_x);
}

// Round 3
// 309.831 us; speedup vs baseline: 1.2096x; 1.0007x over previous
//
#include <hip/hip_runtime.h>
#include <hip/hip_bf16.h>

#define BB 16
#define NN 12
#define NE 144
#define TT 128
#define CC 128

typedef __attribute__((ext_vector_type(8))) short v8s;   // 8 x bf16
typedef __attribute__((ext_vector_type(4))) short v4s;   // 4 x bf16
typedef __attribute__((ext_vector_type(4))) float v4f;   // mfma accumulator

__device__ __forceinline__ short f2bf(float f) {
    unsigned u = __float_as_uint(f);
    u += 0x7fffu + ((u >> 16) & 1u);        // RNE
    return (short)(u >> 16);
}
__device__ __forceinline__ float bf2f(unsigned short u) {
    return __uint_as_float(((unsigned)u) << 16);
}
__device__ __forceinline__ v4s f4_to_bf4(float4 a) {
    v4s r; r[0] = f2bf(a.x); r[1] = f2bf(a.y); r[2] = f2bf(a.z); r[3] = f2bf(a.w); return r;
}
// packed bf16 edge buffer [b][e][t][c]
__device__ __forceinline__ size_t ebfslot(int b, int e, int t) {
    return (((size_t)(b * NE + e) * TT) + t) * CC;
}

// ---------------- weights -> bf16 ----------------
__global__ __launch_bounds__(256) void kW(
    const float* A1, const float* B1, const float* E1, const float* U1, const float* V1,
    const float* A2, const float* B2, const float* E2, const float* U2, const float* V2,
    unsigned short* wb)
{
    int idx = blockIdx.x * 256 + threadIdx.x;   // 10*16384
    int w = idx >> 14, r = idx & 16383;
    const float* s;
    switch (w) {
        case 0: s = A1; break; case 1: s = B1; break; case 2: s = E1; break;
        case 3: s = U1; break; case 4: s = V1; break; case 5: s = A2; break;
        case 6: s = B2; break; case 7: s = E2; break; case 8: s = U2; break;
        default: s = V2; break;
    }
    wb[idx] = (unsigned short)f2bf(s[r]);
}

// ---------------- P: x @ {A,B,V,U}^T  -> bf16 outputs ----------------
__global__ __launch_bounds__(256) void kP(
    const float* __restrict__ x, const unsigned short* __restrict__ wb,
    int sA, int sB, int sV, int sU,
    unsigned short* __restrict__ oA, unsigned short* __restrict__ oB,
    unsigned short* __restrict__ oV, unsigned short* __restrict__ oU)
{
    __shared__ unsigned short xt[64][136];
    int tid = threadIdx.x;
    int m0 = blockIdx.x * 64;
    #pragma unroll
    for (int it = 0; it < 8; ++it) {
        int f = it * 256 + tid;
        int row = f >> 5, c4 = f & 31;
        float4 v = *reinterpret_cast<const float4*>(x + (size_t)m0 * 128 + (size_t)f * 4);
        *reinterpret_cast<v4s*>(&xt[row][c4 * 4]) = f4_to_bf4(v);
    }
    __syncthreads();
    int lane = tid & 63, wid = tid >> 6;
    int l15 = lane & 15, l4 = lane >> 4;

    const unsigned short* Ws[4] = { wb + (size_t)sA * 16384, wb + (size_t)sB * 16384,
                                    wb + (size_t)sV * 16384, wb + (size_t)sU * 16384 };
    unsigned short* Os[4] = { oA, oB, oV, oU };

    #pragma unroll
    for (int w = 0; w < 4; ++w) {
        const unsigned short* W = Ws[w];
        unsigned short* out = Os[w];
        v8s bfr[2][4];
        #pragma unroll
        for (int nt2 = 0; nt2 < 2; ++nt2) {
            int col = (wid * 2 + nt2) * 16 + l15;
            #pragma unroll
            for (int kk = 0; kk < 4; ++kk)
                bfr[nt2][kk] = *reinterpret_cast<const v8s*>(W + col * 128 + kk * 32 + l4 * 8);
        }
        v4f acc[4][2] = {};
        #pragma unroll
        for (int kk = 0; kk < 4; ++kk) {
            #pragma unroll
            for (int mt = 0; mt < 4; ++mt) {
                v8s a = *reinterpret_cast<const v8s*>(&xt[mt * 16 + l15][kk * 32 + l4 * 8]);
                acc[mt][0] = __builtin_amdgcn_mfma_f32_16x16x32_bf16(a, bfr[0][kk], acc[mt][0], 0, 0, 0);
                acc[mt][1] = __builtin_amdgcn_mfma_f32_16x16x32_bf16(a, bfr[1][kk], acc[mt][1], 0, 0, 0);
            }
        }
        #pragma unroll
        for (int mt = 0; mt < 4; ++mt) {
            #pragma unroll
            for (int nt2 = 0; nt2 < 2; ++nt2) {
                int col = (wid * 2 + nt2) * 16 + l15;
                #pragma unroll
                for (int reg = 0; reg < 4; ++reg) {
                    int rowg = m0 + mt * 16 + l4 * 4 + reg;
                    out[(size_t)rowg * 128 + col] = (unsigned short)f2bf(acc[mt][nt2][reg]);
                }
            }
        }
    }
}

// ---------------- A: edge_upd compute + stats + upd store ----------------
// IN_F32: read f32 e0, also emit converted bf16 edges to ebf_out.
template<bool IN_F32>
__global__ __launch_bounds__(256) void kA(
    const float* __restrict__ ef32, const unsigned short* __restrict__ ebf_in,
    unsigned short* __restrict__ ebf_out,
    unsigned short* __restrict__ updg,
    const unsigned short* __restrict__ xA, const unsigned short* __restrict__ xB,
    const unsigned short* __restrict__ Ebf, float* __restrict__ epart)
{
    __shared__ unsigned short ebt[48][136];
    __shared__ unsigned short xab[16][136];
    __shared__ float srow[48], qrow[48];
    int tid = threadIdx.x;
    int bid = blockIdx.x;
    int third = bid % 3; int bt = bid / 3;
    int b = bt >> 7, t = bt & 127;
    if (tid < 48) { srow[tid] = 0.f; qrow[tid] = 0.f; }

    if constexpr (IN_F32) {
        const float* eb = ef32 + ebfslot(b, third * 48, t);
        #pragma unroll
        for (int it = 0; it < 6; ++it) {
            int f = it * 256 + tid;
            int row = f >> 5, c4 = f & 31;
            float4 v = *reinterpret_cast<const float4*>(eb + (size_t)row * (TT * CC) + c4 * 4);
            *reinterpret_cast<v4s*>(&ebt[row][c4 * 4]) = f4_to_bf4(v);
        }
    } else {
        #pragma unroll
        for (int it = 0; it < 3; ++it) {
            int f = it * 256 + tid;
            int row = f >> 4, c8 = f & 15;
            *reinterpret_cast<v8s*>(&ebt[row][c8 * 8]) =
                *reinterpret_cast<const v8s*>(ebf_in + ebfslot(b, third * 48 + row, t) + c8 * 8);
        }
    }
    {   // stage xA (4 rows) + xB (12 rows) bf16 : 256 chunks
        int row = tid >> 4, c8 = tid & 15;
        const unsigned short* src = (row < 4)
            ? (xA + (((size_t)(b * NN + third * 4 + row) * TT) + t) * CC)
            : (xB + (((size_t)(b * NN + (row - 4)) * TT) + t) * CC);
        *reinterpret_cast<v8s*>(&xab[row][c8 * 8]) = *reinterpret_cast<const v8s*>(src + c8 * 8);
    }
    __syncthreads();
    if constexpr (IN_F32) {    // fused e0 -> bf16 global convert (read by kC1/kA2/kC2)
        #pragma unroll
        for (int it = 0; it < 3; ++it) {
            int f = it * 256 + tid;
            int row = f >> 4, c8 = f & 15;
            *reinterpret_cast<v8s*>(ebf_out + ebfslot(b, third * 48 + row, t) + c8 * 8) =
                *reinterpret_cast<const v8s*>(&ebt[row][c8 * 8]);
        }
    }
    int lane = tid & 63, wid = tid >> 6;
    int l15 = lane & 15, l4 = lane >> 4;
    v8s bfr[2][4];
    #pragma unroll
    for (int nt2 = 0; nt2 < 2; ++nt2) {
        int col = (wid * 2 + nt2) * 16 + l15;
        #pragma unroll
        for (int kk = 0; kk < 4; ++kk)
            bfr[nt2][kk] = *reinterpret_cast<const v8s*>(Ebf + col * 128 + kk * 32 + l4 * 8);
    }
    v4f acc[3][2] = {};
    #pragma unroll
    for (int kk = 0; kk < 4; ++kk) {
        #pragma unroll
        for (int mt = 0; mt < 3; ++mt) {
            v8s a = *reinterpret_cast<const v8s*>(&ebt[mt * 16 + l15][kk * 32 + l4 * 8]);
            acc[mt][0] = __builtin_amdgcn_mfma_f32_16x16x32_bf16(a, bfr[0][kk], acc[mt][0], 0, 0, 0);
            acc[mt][1] = __builtin_amdgcn_mfma_f32_16x16x32_bf16(a, bfr[1][kk], acc[mt][1], 0, 0, 0);
        }
    }
    __syncthreads();    // all frag reads (and bf16 copy reads) done before overwrite
    #pragma unroll
    for (int mt = 0; mt < 3; ++mt) {
        #pragma unroll
        for (int reg = 0; reg < 4; ++reg) {
            int r = mt * 16 + l4 * 4 + reg;
            int il = r / 12, jl = r - il * 12;
            float s = 0.f, q = 0.f;
            #pragma unroll
            for (int nt2 = 0; nt2 < 2; ++nt2) {
                int col = (wid * 2 + nt2) * 16 + l15;
                float v = acc[mt][nt2][reg] + bf2f(xab[il][col]) + bf2f(xab[4 + jl][col]);
                s += v; q += v * v;
                ebt[r][col] = (unsigned short)f2bf(v);   // upd tile, reuses e LDS
            }
            #pragma unroll
            for (int off = 1; off < 16; off <<= 1) { s += __shfl_xor(s, off); q += __shfl_xor(q, off); }
            if (l15 == 0) { atomicAdd(&srow[r], s); atomicAdd(&qrow[r], q); }
        }
    }
    __syncthreads();
    #pragma unroll
    for (int it = 0; it < 3; ++it) {    // packed per-block upd tile: fully contiguous
        int f = it * 256 + tid;
        int row = f >> 4, c8 = f & 15;
        *reinterpret_cast<v8s*>(updg + (size_t)bid * 6144 + (size_t)f * 8) =
            *reinterpret_cast<const v8s*>(&ebt[row][c8 * 8]);
    }
    if (tid < 48) {
        epart[(size_t)bid * 96 + tid * 2 + 0] = srow[tid];
        epart[(size_t)bid * 96 + tid * 2 + 1] = qrow[tid];
    }
}

// ---------------- reduce edge stats -> scale/shift ----------------
__global__ __launch_bounds__(256) void kRede(
    const float* __restrict__ epart, const float* __restrict__ g,
    const float* __restrict__ be, float* __restrict__ estats)
{
    int e = blockIdx.x;              // 0..143
    int third = e / 48, le = e % 48;
    float s = 0.f, q = 0.f;
    for (int bt = threadIdx.x; bt < 2048; bt += 256) {
        const float* p = epart + ((size_t)(bt * 3 + third) * 96 + le * 2);
        s += p[0]; q += p[1];
    }
    __shared__ float ss[4], qq[4];
    #pragma unroll
    for (int off = 32; off >= 1; off >>= 1) { s += __shfl_down(s, off); q += __shfl_down(q, off); }
    int wid = threadIdx.x >> 6;
    if ((threadIdx.x & 63) == 0) { ss[wid] = s; qq[wid] = q; }
    __syncthreads();
    if (threadIdx.x == 0) {
        s = ss[0] + ss[1] + ss[2] + ss[3];
        q = qq[0] + qq[1] + qq[2] + qq[3];
        const float M = 262144.f;    // B*T*C
        float mean = s / M;
        float var = q / M - mean * mean;
        float sc = g[e] * rsqrtf(var + 1e-5f);
        estats[e * 2] = sc;
        estats[e * 2 + 1] = be[e] - mean * sc;
    }
}

// ---------------- C: elementwise edge update + softmax + agg ----------------
template<bool OUT_F32>
__global__ __launch_bounds__(256) void kC(
    const unsigned short* __restrict__ ebf,    // bf16 packed edges (in)
    unsigned short* __restrict__ ebf_out,      // bf16 write-back (L1; == ebf)
    float* __restrict__ eout,                  // f32 final (L2)
    const unsigned short* __restrict__ updg,
    const unsigned short* __restrict__ xV, const unsigned short* __restrict__ xU,
    const float* __restrict__ estats,
    unsigned short* __restrict__ yout, float* __restrict__ npart)
{
    __shared__ unsigned short se[48][136];
    __shared__ unsigned short xv[12][136];
    __shared__ float scs[48], shs[48];
    __shared__ float ns[4], nq[4];
    int tid = threadIdx.x;
    int bid = blockIdx.x;
    int third = bid % 3; int bt = bid / 3;
    int b = bt >> 7, t = bt & 127;
    if (tid < 48) { scs[tid] = estats[(third * 48 + tid) * 2]; shs[tid] = estats[(third * 48 + tid) * 2 + 1]; }
    if (tid < 4) { ns[tid] = 0.f; nq[tid] = 0.f; }
    if (tid < 192) {    // stage xV : 12 rows
        int row = tid >> 4, c8 = tid & 15;
        *reinterpret_cast<v8s*>(&xv[row][c8 * 8]) =
            *reinterpret_cast<const v8s*>(xV + (((size_t)(b * NN + row) * TT) + t) * CC + c8 * 8);
    }
    __syncthreads();
    #pragma unroll
    for (int it = 0; it < 3; ++it) {
        int f = it * 256 + tid;
        int row = f >> 4, c8 = f & 15;
        int eg = third * 48 + row;
        v8s uv = *reinterpret_cast<const v8s*>(updg + (size_t)bid * 6144 + (size_t)f * 8);
        size_t slot = ebfslot(b, eg, t) + c8 * 8;
        v8s evv = *reinterpret_cast<const v8s*>(ebf + slot);
        float sc = scs[row], sh = shs[row];
        float en[8];
        v8s nv;
        #pragma unroll
        for (int k = 0; k < 8; ++k) {
            en[k] = bf2f((unsigned short)evv[k]) + fmaxf(sc * bf2f((unsigned short)uv[k]) + sh, 0.f);
            nv[k] = f2bf(en[k]);
        }
        *reinterpret_cast<v8s*>(&se[row][c8 * 8]) = nv;
        if constexpr (OUT_F32) {
            size_t off = (((size_t)(b * NE + eg) * TT) + t) * CC + c8 * 8;
            *reinterpret_cast<float4*>(eout + off)     = make_float4(en[0], en[1], en[2], en[3]);
            *reinterpret_cast<float4*>(eout + off + 4) = make_float4(en[4], en[5], en[6], en[7]);
        } else {
            *reinterpret_cast<v8s*>(ebf_out + slot) = nv;
        }
    }
    __syncthreads();
    int lane = tid & 63;
    #pragma unroll
    for (int ph = 0; ph < 2; ++ph) {
        int unit = tid + ph * 256;       // 512 units = 4 i_loc * 128 c
        int il = unit >> 7, c = unit & 127;
        float den = 0.f, ag = 0.f;
        #pragma unroll
        for (int j = 0; j < 12; ++j) {
            float sv = bf2f(se[il * 12 + j][c]);
            float sg = 1.f / (1.f + __expf(-sv));
            float ev = __expf(sg);
            den += ev;
            ag += ev * bf2f(xv[j][c]);
        }
        float agg = ag / (den * 12.f);
        int i = third * 4 + il;
        size_t xa = (((size_t)(b * NN + i) * TT) + t) * CC + c;
        float yv = bf2f(xU[xa]) + agg;
        unsigned short us = (unsigned short)f2bf(yv);
        yout[xa] = us;
        float yr = bf2f(us);
        float s1 = yr, s2 = yr * yr;
        #pragma unroll
        for (int off = 1; off < 64; off <<= 1) { s1 += __shfl_xor(s1, off); s2 += __shfl_xor(s2, off); }
        if (lane == 0) { atomicAdd(&ns[il], s1); atomicAdd(&nq[il], s2); }
    }
    __syncthreads();
    if (tid < 4) {
        npart[(size_t)bid * 8 + tid * 2 + 0] = ns[tid];
        npart[(size_t)bid * 8 + tid * 2 + 1] = nq[tid];
    }
}

// ---------------- reduce node stats ----------------
__global__ __launch_bounds__(256) void kRedn(
    const float* __restrict__ npart, const float* __restrict__ g,
    const float* __restrict__ be, float* __restrict__ nstats)
{
    int n = blockIdx.x;             // 0..11
    int third = n >> 2, il = n & 3;
    float s = 0.f, q = 0.f;
    for (int bt = threadIdx.x; bt < 2048; bt += 256) {
        const float* p = npart + ((size_t)(bt * 3 + third) * 8 + il * 2);
        s += p[0]; q += p[1];
    }
    __shared__ float ss[4], qq[4];
    #pragma unroll
    for (int off = 32; off >= 1; off >>= 1) { s += __shfl_down(s, off); q += __shfl_down(q, off); }
    int wid = threadIdx.x >> 6;
    if ((threadIdx.x & 63) == 0) { ss[wid] = s; qq[wid] = q; }
    __syncthreads();
    if (threadIdx.x == 0) {
        s = ss[0] + ss[1] + ss[2] + ss[3];
        q = qq[0] + qq[1] + qq[2] + qq[3];
        const float M = 262144.f;   // B*T*C
        float mean = s / M;
        float var = q / M - mean * mean;
        float sc = g[n] * rsqrtf(var + 1e-5f);
        nstats[n * 2] = sc;
        nstats[n * 2 + 1] = be[n] - mean * sc;
    }
}

// ---------------- E: node BN + residual + relu ----------------
__global__ __launch_bounds__(256) void kE(
    const float* xres, const unsigned short* __restrict__ yin,
    const float* __restrict__ nstats, float* xout)
{
    int idx4 = blockIdx.x * 256 + threadIdx.x;     // 786432 float4s
    size_t base = (size_t)idx4 * 4;
    int n = (int)((base >> 14) % 12);
    float scv = nstats[n * 2], shv = nstats[n * 2 + 1];
    float4 xv = *reinterpret_cast<const float4*>(xres + base);
    v4s yv4 = *reinterpret_cast<const v4s*>(yin + base);
    float4 o;
    o.x = fmaxf(xv.x + scv * bf2f((unsigned short)yv4[0]) + shv, 0.f);
    o.y = fmaxf(xv.y + scv * bf2f((unsigned short)yv4[1]) + shv, 0.f);
    o.z = fmaxf(xv.z + scv * bf2f((unsigned short)yv4[2]) + shv, 0.f);
    o.w = fmaxf(xv.w + scv * bf2f((unsigned short)yv4[3]) + shv, 0.f);
    *reinterpret_cast<float4*>(xout + base) = o;
}

extern "C" void kernel_launch(void* const* d_in, const int* in_sizes, int n_in,
                              void* d_out, int out_size, void* d_ws, size_t ws_size,
                              hipStream_t stream)
{
    const float* x0 = (const float*)d_in[0];
    const float* e0 = (const float*)d_in[1];
    const float* W[10];
    for (int i = 0; i < 10; ++i) W[i] = (const float*)d_in[2 + i];
    const float* ge1 = (const float*)d_in[12];
    const float* be1 = (const float*)d_in[13];
    const float* gv1 = (const float*)d_in[14];
    const float* bv1 = (const float*)d_in[15];
    const float* ge2 = (const float*)d_in[16];
    const float* be2 = (const float*)d_in[17];
    const float* gv2 = (const float*)d_in[18];
    const float* bv2 = (const float*)d_in[19];

    const size_t SZX = (size_t)BB * NN * TT * CC;   // 3145728
    const size_t SZE = (size_t)BB * NE * TT * CC;   // 37748736
    float* out_x = (float*)d_out;
    float* out_e = out_x + SZX;

    unsigned short* ws16 = (unsigned short*)d_ws;
    unsigned short* xA = ws16;
    unsigned short* xB = ws16 + SZX;
    unsigned short* xV = ws16 + 2 * SZX;
    unsigned short* xU = ws16 + 3 * SZX;
    unsigned short* yb = ws16 + 4 * SZX;
    unsigned short* ebf = ws16 + 5 * SZX;          // bf16 edge buffer
    unsigned short* upd = ebf + SZE;               // bf16 edge_upd buffer
    float* fpart  = (float*)(upd + SZE);
    float* epart  = fpart;                 // 6144*96
    float* estats = epart + 589824;        // 288
    float* npart  = estats + 288;          // 6144*8
    float* nstats = npart + 49152;         // 24
    unsigned short* wb = (unsigned short*)(nstats + 24);   // 10*16384 bf16

    float* x1 = out_x;   // layer-1 x output scratch (rewritten in-place by kE2)

    kW<<<640, 256, 0, stream>>>(W[0], W[1], W[2], W[3], W[4], W[5], W[6], W[7], W[8], W[9], wb);

    // ---- layer 1 ----
    kP<<<384, 256, 0, stream>>>(x0, wb, 0, 1, 4, 3, xA, xB, xV, xU);
    kA<true><<<6144, 256, 0, stream>>>(e0, nullptr, ebf, upd, xA, xB, wb + 2 * 16384, epart);
    kRede<<<144, 256, 0, stream>>>(epart, ge1, be1, estats);
    kC<false><<<6144, 256, 0, stream>>>(ebf, ebf, nullptr, upd, xV, xU, estats, yb, npart);
    kRedn<<<12, 256, 0, stream>>>(npart, gv1, bv1, nstats);
    kE<<<3072, 256, 0, stream>>>(x0, yb, nstats, x1);

    // ---- layer 2 ----
    kP<<<384, 256, 0, stream>>>(x1, wb, 5, 6, 9, 8, xA, xB, xV, xU);
    kA<false><<<6144, 256, 0, stream>>>(nullptr, ebf, nullptr, upd, xA, xB, wb + 7 * 16384, epart);
    kRede<<<144, 256, 0, stream>>>(epart, ge2, be2, estats);
    kC<true><<<6144, 256, 0, stream>>>(ebf, nullptr, out_e, upd, xV, xU, estats, yb, npart);
    kRedn<<<12, 256, 0, stream>>>(npart, gv2, bv2, nstats);
    kE<<<3072, 256, 0, stream>>>(x1, yb, nstats, out_x);
}